// Round 12
// baseline (54.338 us; speedup 1.0000x reference)
//
#include <hip/hip_runtime.h>
#include <math.h>

#define P 7
#define PP (P * P)
#define C 256
#define H 64
#define W 64
#define S (H * W)
#define R_MAX 1024

#define CHALF 128             // channels per fused block (half of C)
#define LPAD 130              // LDS row pad (128 + 2): float2 writes land 2-way (free)

// ---------------------------------------------------------------------------
// Transpose [N, C, S] -> [N, S, C], 64x64 tiles, float4 global on BOTH sides.
// Block (0,0,0) additionally computes the roi->slot permutation (stable
// counting sort by image id) -- runs concurrently, saving a dispatch.
// ---------------------------------------------------------------------------
#define TT 64
#define TPAD 65
__global__ __launch_bounds__(256) void transpose_bucket_kernel(
    const float* __restrict__ in, float* __restrict__ outT,
    const float* __restrict__ rois, int* __restrict__ perm, int R)
{
    __shared__ float tile[TT * TPAD];      // 16.6 KB
    const int b   = blockIdx.z;
    const int s0  = blockIdx.x * TT;
    const int c0  = blockIdx.y * TT;
    const int t   = threadIdx.x;
    const int r16 = t >> 4;                // 0..15
    const int m16 = (t & 15) * 4;          // 0,4,...,60

    #pragma unroll
    for (int k = 0; k < 4; ++k) {
        const int cl = r16 + 16 * k;
        const float4 v = *(const float4*)(in + (size_t)(b * C + c0 + cl) * S + s0 + m16);
        tile[cl * TPAD + m16 + 0] = v.x;
        tile[cl * TPAD + m16 + 1] = v.y;
        tile[cl * TPAD + m16 + 2] = v.z;
        tile[cl * TPAD + m16 + 3] = v.w;
    }
    __syncthreads();
    #pragma unroll
    for (int k = 0; k < 4; ++k) {
        const int sl = r16 + 16 * k;
        float4 v;
        v.x = tile[(m16 + 0) * TPAD + sl];
        v.y = tile[(m16 + 1) * TPAD + sl];
        v.z = tile[(m16 + 2) * TPAD + sl];
        v.w = tile[(m16 + 3) * TPAD + sl];
        *(float4*)(outT + (size_t)(b * S + s0 + sl) * C + c0 + m16) = v;
    }

    if (blockIdx.x == 0 && blockIdx.y == 0 && blockIdx.z == 0 && R > 0 && R <= R_MAX) {
        __shared__ int bimg[R_MAX];        // 4 KB
        for (int i = t; i < R; i += 256)
            bimg[i] = (int)rois[(size_t)i * 5];
        __syncthreads();
        for (int i = t; i < R; i += 256) {
            const int myb = bimg[i];
            int pos = 0;
            for (int k = 0; k < R; ++k) {
                const int bk = bimg[k];
                pos += (bk < myb) || (bk == myb && k < i);
            }
            perm[pos] = i;
        }
    }
}

// ---------------------------------------------------------------------------
// Fused RoI max-pool + coalesced output write.
// Block = (rslot, 128-channel half), 512 threads = 8 waves.
// wave = cell (round-robin over 49 cells, ~6 each): uniform bins per wave,
// 64 lanes x float2 = the 128-channel half, 512B contiguous per wave-load.
// Inner loop = R10's 2x2 clamped batch (4 independent loads per wait,
// bounded duplicate amplification -- R11 showed big unrolls lose on load
// throughput). Maxes staged in LDS [49][130], then the block writes
// out[r, c0..c0+127, 0..48] = 6272 contiguous floats (float4 stores).
// Eliminates the reorder kernel and the ws2 round-trip entirely.
// ---------------------------------------------------------------------------
__global__ __launch_bounds__(512) void roi_pool_out_kernel(
    const float* __restrict__ ft,    // [N, H, W, C]
    const float* __restrict__ rois,
    const int*   __restrict__ perm,
    float* __restrict__ out)         // [R, C, P, P]
{
    __shared__ float lds[PP * LPAD];      // 49*130*4 = 25.5 KB

    const int l   = blockIdx.x;
    const int nwg = gridDim.x;            // 2R
    const int work  = ((nwg & 7) == 0) ? ((l & 7) * (nwg >> 3) + (l >> 3)) : l;
    const int rslot = work >> 1;
    const int half  = work & 1;
    const int wave  = threadIdx.x >> 6;   // 0..7
    const int lane  = threadIdx.x & 63;
    const int c0    = half * CHALF;

    const int r = perm[rslot];
    const float* roi = rois + (size_t)r * 5;
    const int b = (int)roi[0];
    // jnp.round is half-to-even; rintf matches (RNE); *2^-5 scale is exact.
    int x0 = (int)rintf(roi[1] * 0.03125f);
    int y0 = (int)rintf(roi[2] * 0.03125f);
    int x1 = (int)rintf(roi[3] * 0.03125f);
    int y1 = (int)rintf(roi[4] * 0.03125f);
    x0 = min(max(x0, 0), W - 1);
    y0 = min(max(y0, 0), H - 1);
    x1 = min(max(x1, 0), W - 1);
    y1 = min(max(y1, 0), H - 1);

    const bool valid = (x0 < x1) && (y0 < y1);

    if (valid) {
        const int Lh = x1 - x0;  // x-range bins the H axis (reference quirk)
        const int Lw = y1 - y0;  // y-range bins the W axis
        for (int cell = wave; cell < PP; cell += 8) {
            const int i = cell / P;
            const int j = cell - P * i;

            const int hs = x0 + (i * Lh) / P;
            const int he = x0 + ((i + 1) * Lh + (P - 1)) / P;
            const int ws = y0 + (j * Lw) / P;
            const int we = y0 + ((j + 1) * Lw + (P - 1)) / P;
            const int bh = he - hs;       // >= 1
            const int bw = we - ws;       // >= 1

            const float* base = ft + (((size_t)b * H + hs) * W + ws) * C + c0 + lane * 2;

            float mx = -INFINITY, my = -INFINITY;
            for (int h = 0; h < bh; h += 2) {
                const int h2 = min(h + 1, bh - 1);        // clamp: dup row no-op for max
                const float* r0 = base + (size_t)h  * (W * C);
                const float* r1 = base + (size_t)h2 * (W * C);
                for (int w = 0; w < bw; w += 2) {
                    const int w2 = min(w + 1, bw - 1);    // clamp: dup col no-op
                    const float2 a  = *(const float2*)(r0 + (size_t)w  * C);
                    const float2 bb = *(const float2*)(r0 + (size_t)w2 * C);
                    const float2 cc = *(const float2*)(r1 + (size_t)w  * C);
                    const float2 dd = *(const float2*)(r1 + (size_t)w2 * C);
                    mx = fmaxf(fmaxf(fmaxf(mx, a.x), fmaxf(bb.x, cc.x)), dd.x);
                    my = fmaxf(fmaxf(fmaxf(my, a.y), fmaxf(bb.y, cc.y)), dd.y);
                }
            }
            lds[cell * LPAD + lane * 2 + 0] = mx;
            lds[cell * LPAD + lane * 2 + 1] = my;
        }
    } else {
        for (int cell = wave; cell < PP; cell += 8) {
            lds[cell * LPAD + lane * 2 + 0] = 0.0f;
            lds[cell * LPAD + lane * 2 + 1] = 0.0f;
        }
    }

    __syncthreads();

    // Write out[r, c0..c0+127, 0..48]: 6272 contiguous floats = 1568 float4.
    float* dst = out + ((size_t)r * C + c0) * PP;
    const int nq = (CHALF * PP) / 4;      // 1568
    #pragma unroll
    for (int k = 0; k < 4; ++k) {
        const int qf = threadIdx.x + 512 * k;
        if (qf < nq) {
            float v[4];
            #pragma unroll
            for (int m = 0; m < 4; ++m) {
                const int idx  = 4 * qf + m;
                const int c    = idx / PP;
                const int cell = idx - PP * c;
                v[m] = lds[cell * LPAD + c];
            }
            *(float4*)(dst + 4 * qf) = make_float4(v[0], v[1], v[2], v[3]);
        }
    }
}

// ---------------------------------------------------------------------------
// Fallback tier 1: pool with direct strided out writes (no perm needed)
// ---------------------------------------------------------------------------
__global__ __launch_bounds__(64) void roi_pool_cell_direct_kernel(
    const float* __restrict__ ft, const float* __restrict__ rois,
    float* __restrict__ out)
{
    const int bid = blockIdx.x;
    const int r   = bid / PP;
    const int rem = bid % PP;
    const int i   = rem / P;
    const int j   = rem % P;
    const int c4  = threadIdx.x;

    const float* roi = rois + (size_t)r * 5;
    const int b = (int)roi[0];
    int x0 = (int)rintf(roi[1] * 0.03125f);
    int y0 = (int)rintf(roi[2] * 0.03125f);
    int x1 = (int)rintf(roi[3] * 0.03125f);
    int y1 = (int)rintf(roi[4] * 0.03125f);
    x0 = min(max(x0, 0), W - 1);
    y0 = min(max(y0, 0), H - 1);
    x1 = min(max(x1, 0), W - 1);
    y1 = min(max(y1, 0), H - 1);

    float* o = out + (((size_t)r * C + c4 * 4) * P + i) * P + j;
    if (!((x0 < x1) && (y0 < y1))) {
        o[0] = 0.0f; o[PP] = 0.0f; o[2 * PP] = 0.0f; o[3 * PP] = 0.0f;
        return;
    }
    const int Lh = x1 - x0, Lw = y1 - y0;
    const int hs = x0 + (i * Lh) / P;
    const int he = x0 + ((i + 1) * Lh + (P - 1)) / P;
    const int ws = y0 + (j * Lw) / P;
    const int we = y0 + ((j + 1) * Lw + (P - 1)) / P;
    const int bh = he - hs, bw = we - ws;
    const float* base = ft + (((size_t)b * H + hs) * W + ws) * C + c4 * 4;
    float mx = -INFINITY, my = -INFINITY, mz = -INFINITY, mw = -INFINITY;
    for (int h = 0; h < bh; h += 2) {
        const int h2 = min(h + 1, bh - 1);
        const float* r0 = base + (size_t)h  * (W * C);
        const float* r1 = base + (size_t)h2 * (W * C);
        for (int w = 0; w < bw; w += 2) {
            const int w2 = min(w + 1, bw - 1);
            const float4 a  = *(const float4*)(r0 + (size_t)w  * C);
            const float4 bb = *(const float4*)(r0 + (size_t)w2 * C);
            const float4 cc = *(const float4*)(r1 + (size_t)w  * C);
            const float4 dd = *(const float4*)(r1 + (size_t)w2 * C);
            mx = fmaxf(fmaxf(fmaxf(mx, a.x), fmaxf(bb.x, cc.x)), dd.x);
            my = fmaxf(fmaxf(fmaxf(my, a.y), fmaxf(bb.y, cc.y)), dd.y);
            mz = fmaxf(fmaxf(fmaxf(mz, a.z), fmaxf(bb.z, cc.z)), dd.z);
            mw = fmaxf(fmaxf(fmaxf(mw, a.w), fmaxf(bb.w, cc.w)), dd.w);
        }
    }
    o[0] = mx; o[PP] = my; o[2 * PP] = mz; o[3 * PP] = mw;
}

// ---------------------------------------------------------------------------
// Fallback tier 2: no workspace
// ---------------------------------------------------------------------------
__global__ __launch_bounds__(256) void roi_pool_naive_kernel(
    const float* __restrict__ features, const float* __restrict__ rois,
    float* __restrict__ out)
{
    const int rb = blockIdx.x;
    const int r = rb / P;
    const int i = rb % P;
    const int c = threadIdx.x;

    const float* roi = rois + (size_t)r * 5;
    const int b = (int)roi[0];
    int x0 = (int)rintf(roi[1] * 0.03125f);
    int y0 = (int)rintf(roi[2] * 0.03125f);
    int x1 = (int)rintf(roi[3] * 0.03125f);
    int y1 = (int)rintf(roi[4] * 0.03125f);
    x0 = min(max(x0, 0), W - 1);
    y0 = min(max(y0, 0), H - 1);
    x1 = min(max(x1, 0), W - 1);
    y1 = min(max(y1, 0), H - 1);

    const bool valid = (x0 < x1) && (y0 < y1);
    float* o = out + (((size_t)r * C + c) * P + i) * P;
    if (!valid) {
        #pragma unroll
        for (int j = 0; j < P; ++j) o[j] = 0.0f;
        return;
    }
    const int Lh = x1 - x0, Lw = y1 - y0;
    const int hs = x0 + (i * Lh) / P;
    const int he = x0 + ((i + 1) * Lh + (P - 1)) / P;
    int ws_[P], we_[P];
    #pragma unroll
    for (int j = 0; j < P; ++j) {
        ws_[j] = y0 + (j * Lw) / P;
        we_[j] = y0 + ((j + 1) * Lw + (P - 1)) / P;
    }
    float acc[P];
    #pragma unroll
    for (int j = 0; j < P; ++j) acc[j] = -INFINITY;
    const float* f = features + (((size_t)b * C + c) * H) * W;
    for (int h = hs; h < he; ++h) {
        const float* row = f + h * W;
        #pragma unroll
        for (int j = 0; j < P; ++j) {
            float m = acc[j];
            for (int w = ws_[j]; w < we_[j]; ++w) m = fmaxf(m, row[w]);
            acc[j] = m;
        }
    }
    #pragma unroll
    for (int j = 0; j < P; ++j) o[j] = acc[j];
}

extern "C" void kernel_launch(void* const* d_in, const int* in_sizes, int n_in,
                              void* d_out, int out_size, void* d_ws, size_t ws_size,
                              hipStream_t stream)
{
    const float* features = (const float*)d_in[0];
    const float* rois     = (const float*)d_in[1];
    float* out = (float*)d_out;

    const int R = in_sizes[1] / 5;                  // 256
    const int N = in_sizes[0] / (C * S);            // 4

    const size_t ft_bytes   = (size_t)N * C * S * sizeof(float);   // 16 MB
    const size_t perm_bytes = (size_t)R * sizeof(int);
    const size_t full_need  = ft_bytes + perm_bytes;

    if (ws_size >= full_need && R <= R_MAX) {
        float* ft  = (float*)d_ws;
        int*  perm = (int*)((char*)d_ws + ft_bytes);

        dim3 tgrid(S / TT, C / TT, N);              // 64 x 4 x 4 = 1024 blocks
        transpose_bucket_kernel<<<tgrid, 256, 0, stream>>>(features, ft, rois, perm, R);
        roi_pool_out_kernel<<<R * 2, 512, 0, stream>>>(ft, rois, perm, out);
    } else if (ws_size >= ft_bytes) {
        float* ft = (float*)d_ws;
        dim3 tgrid(S / TT, C / TT, N);
        transpose_bucket_kernel<<<tgrid, 256, 0, stream>>>(features, ft, rois, (int*)nullptr, 0);
        roi_pool_cell_direct_kernel<<<R * PP, 64, 0, stream>>>(ft, rois, out);
    } else {
        roi_pool_naive_kernel<<<R * P, C, 0, stream>>>(features, rois, out);
    }
}

// Round 13
// 36.551 us; speedup vs baseline: 1.4866x; 1.4866x over previous
//
#include <hip/hip_runtime.h>
#include <math.h>

#define P 7
#define PP (P * P)
#define C 256
#define H 64
#define W 64
#define S (H * W)
#define R_MAX 1024

#define NCP 25                // cell-pairs per roi (49 cells -> 25 pairs)
#define RPAD 257              // reorder LDS pad: [cell][channel<=255], +1 anti-conflict

typedef unsigned short ushort_t;
typedef unsigned int uint_t;

// --- bf16 helpers: pack with RNE, unpack via shift/mask (2 VALU / 2 values) ---
__device__ __forceinline__ float bflo(uint_t u) { return __uint_as_float(u << 16); }
__device__ __forceinline__ float bfhi(uint_t u) { return __uint_as_float(u & 0xffff0000u); }
__device__ __forceinline__ uint_t pack2_bf16(float a, float b) {
    uint_t ua = __float_as_uint(a), ub = __float_as_uint(b);
    ua = (ua + 0x7fffu + ((ua >> 16) & 1u)) >> 16;           // RNE
    ub = (ub + 0x7fffu + ((ub >> 16) & 1u)) >> 16;
    return ua | (ub << 16);
}

// ---------------------------------------------------------------------------
// Transpose [N, C, S] f32 -> [N, S, C] bf16, 64x64 tiles, float4 reads,
// uint2 (4xbf16) writes. Block (0,0,0) also computes the roi->slot
// permutation (stable counting sort by image id), concurrent with the rest.
// ---------------------------------------------------------------------------
#define TT 64
#define TPAD 65
__global__ __launch_bounds__(256) void transpose_bucket_kernel(
    const float* __restrict__ in, ushort_t* __restrict__ outT,
    const float* __restrict__ rois, int* __restrict__ perm, int R)
{
    __shared__ float tile[TT * TPAD];      // 16.6 KB
    const int b   = blockIdx.z;
    const int s0  = blockIdx.x * TT;
    const int c0  = blockIdx.y * TT;
    const int t   = threadIdx.x;
    const int r16 = t >> 4;                // 0..15
    const int m16 = (t & 15) * 4;          // 0,4,...,60

    #pragma unroll
    for (int k = 0; k < 4; ++k) {
        const int cl = r16 + 16 * k;
        const float4 v = *(const float4*)(in + (size_t)(b * C + c0 + cl) * S + s0 + m16);
        tile[cl * TPAD + m16 + 0] = v.x;
        tile[cl * TPAD + m16 + 1] = v.y;
        tile[cl * TPAD + m16 + 2] = v.z;
        tile[cl * TPAD + m16 + 3] = v.w;
    }
    __syncthreads();
    #pragma unroll
    for (int k = 0; k < 4; ++k) {
        const int sl = r16 + 16 * k;
        uint2 o;
        o.x = pack2_bf16(tile[(m16 + 0) * TPAD + sl], tile[(m16 + 1) * TPAD + sl]);
        o.y = pack2_bf16(tile[(m16 + 2) * TPAD + sl], tile[(m16 + 3) * TPAD + sl]);
        *(uint2*)(outT + (size_t)(b * S + s0 + sl) * C + c0 + m16) = o;
    }

    if (blockIdx.x == 0 && blockIdx.y == 0 && blockIdx.z == 0 && R > 0 && R <= R_MAX) {
        __shared__ int bimg[R_MAX];        // 4 KB
        for (int i = t; i < R; i += 256)
            bimg[i] = (int)rois[(size_t)i * 5];
        __syncthreads();
        for (int i = t; i < R; i += 256) {
            const int myb = bimg[i];
            int pos = 0;
            for (int k = 0; k < R; ++k) {
                const int bk = bimg[k];
                pos += (bk < myb) || (bk == myb && k < i);
            }
            perm[pos] = i;
        }
    }
}

// ---------------------------------------------------------------------------
// RoI max-pool (R10 structure, bf16 ft): block = (rslot, cell-PAIR),
// 128 threads = 2 waves, wave = cell (uniform bins -> no divergence),
// lane = 4-channel group (uint2 = 4 bf16 = 8B; 512B contiguous per
// wave-load). 2x2 clamped batches = 4 independent loads per vmcnt wait.
// Writes ws2[rslot, cell, C] bf16 contiguous (512B per wave).
// Chunked XCD swizzle: 800 works/chunk = 32 whole rois -> each roi's 25
// blocks land on ONE XCD; image-sorted rois keep ~one 8MB(bf16->4MB) image
// per XCD L2.
// ---------------------------------------------------------------------------
__global__ __launch_bounds__(128) void roi_pool_cell_kernel(
    const ushort_t* __restrict__ ft,  // [N, H, W, C] bf16
    const float* __restrict__ rois,
    const int*   __restrict__ perm,
    ushort_t* __restrict__ ws2)       // [R, PP, C] bf16
{
    const int l   = blockIdx.x;
    const int nwg = gridDim.x;            // R * NCP
    const int work  = ((nwg & 7) == 0) ? ((l & 7) * (nwg >> 3) + (l >> 3)) : l;
    const int rslot = work / NCP;
    const int cp    = work % NCP;
    const int cell  = 2 * cp + (threadIdx.x >> 6);
    const int q     = threadIdx.x & 63;   // channel quad 0..63

    if (cell >= PP) return;               // wave-uniform tail exit

    const int r = perm[rslot];
    const float* roi = rois + (size_t)r * 5;
    const int b = (int)roi[0];
    // jnp.round is half-to-even; rintf matches (RNE); *2^-5 scale is exact.
    int x0 = (int)rintf(roi[1] * 0.03125f);
    int y0 = (int)rintf(roi[2] * 0.03125f);
    int x1 = (int)rintf(roi[3] * 0.03125f);
    int y1 = (int)rintf(roi[4] * 0.03125f);
    x0 = min(max(x0, 0), W - 1);
    y0 = min(max(y0, 0), H - 1);
    x1 = min(max(x1, 0), W - 1);
    y1 = min(max(y1, 0), H - 1);

    uint2* o = (uint2*)(ws2 + ((size_t)rslot * PP + cell) * C) + q;

    if (!((x0 < x1) && (y0 < y1))) {
        *o = make_uint2(0u, 0u);          // bf16 zeros
        return;
    }

    const int Lh = x1 - x0;  // x-range bins the H axis (reference quirk)
    const int Lw = y1 - y0;  // y-range bins the W axis
    const int i  = cell / P;
    const int j  = cell - P * i;

    const int hs = x0 + (i * Lh) / P;
    const int he = x0 + ((i + 1) * Lh + (P - 1)) / P;
    const int ws = y0 + (j * Lw) / P;
    const int we = y0 + ((j + 1) * Lw + (P - 1)) / P;
    const int bh = he - hs;               // >= 1
    const int bw = we - ws;               // >= 1

    const ushort_t* base = ft + (((size_t)b * H + hs) * W + ws) * C + q * 4;

    float m0 = -INFINITY, m1 = -INFINITY, m2 = -INFINITY, m3 = -INFINITY;
    for (int h = 0; h < bh; h += 2) {
        const int h2 = min(h + 1, bh - 1);       // clamp: dup row no-op for max
        const ushort_t* r0 = base + (size_t)h  * (W * C);
        const ushort_t* r1 = base + (size_t)h2 * (W * C);
        for (int w = 0; w < bw; w += 2) {
            const int w2 = min(w + 1, bw - 1);   // clamp: dup col no-op
            const uint2 a  = *(const uint2*)(r0 + (size_t)w  * C);
            const uint2 bb = *(const uint2*)(r0 + (size_t)w2 * C);
            const uint2 cc = *(const uint2*)(r1 + (size_t)w  * C);
            const uint2 dd = *(const uint2*)(r1 + (size_t)w2 * C);
            m0 = fmaxf(fmaxf(fmaxf(m0, bflo(a.x)), fmaxf(bflo(bb.x), bflo(cc.x))), bflo(dd.x));
            m1 = fmaxf(fmaxf(fmaxf(m1, bfhi(a.x)), fmaxf(bfhi(bb.x), bfhi(cc.x))), bfhi(dd.x));
            m2 = fmaxf(fmaxf(fmaxf(m2, bflo(a.y)), fmaxf(bflo(bb.y), bflo(cc.y))), bflo(dd.y));
            m3 = fmaxf(fmaxf(fmaxf(m3, bfhi(a.y)), fmaxf(bfhi(bb.y), bfhi(cc.y))), bfhi(dd.y));
        }
    }

    // values are already bf16-representable; repack is exact
    *o = make_uint2(pack2_bf16(m0, m1), pack2_bf16(m2, m3));
}

// ---------------------------------------------------------------------------
// Reorder ws2[rslot, cell, C] bf16 -> out[r, C, cell] f32 via LDS; both
// sides coalesced, out written as full-line float4 stores.
// ---------------------------------------------------------------------------
__global__ __launch_bounds__(256) void reorder_kernel(
    const ushort_t* __restrict__ ws2,
    const int*      __restrict__ perm,
    float* __restrict__ out)         // [R, C, PP]
{
    __shared__ float lds[PP * RPAD];   // 50.4 KB
    const int l = blockIdx.x;
    const int R = gridDim.x;
    const int rslot = ((R & 7) == 0) ? ((l & 7) * (R >> 3) + (l >> 3)) : l;
    const int r = perm[rslot];
    const int t = threadIdx.x;

    const uint_t* src32 = (const uint_t*)(ws2 + (size_t)rslot * PP * C);
    for (int idx = t; idx < PP * (C / 2); idx += 256) {   // 6272 u32 loads
        const int cell = idx >> 7;        // /128
        const int cpr  = idx & 127;
        const uint_t u = src32[idx];
        lds[cell * RPAD + 2 * cpr + 0] = bflo(u);
        lds[cell * RPAD + 2 * cpr + 1] = bfhi(u);
    }

    __syncthreads();

    float* dst = out + (size_t)r * C * PP;
    const int nq = (C * PP) / 4;     // 3136 float4s
    #pragma unroll
    for (int k = 0; k < 13; ++k) {
        const int q = t + 256 * k;
        if (q < nq) {
            float v[4];
            #pragma unroll
            for (int m = 0; m < 4; ++m) {
                const int idx  = 4 * q + m;
                const int c    = idx / PP;
                const int cell = idx % PP;
                v[m] = lds[cell * RPAD + c];
            }
            *(float4*)(dst + 4 * q) = make_float4(v[0], v[1], v[2], v[3]);
        }
    }
}

// ---------------------------------------------------------------------------
// Fallback tier 1: pool (bf16 ft) with direct strided out writes
// ---------------------------------------------------------------------------
__global__ __launch_bounds__(64) void roi_pool_cell_direct_kernel(
    const ushort_t* __restrict__ ft, const float* __restrict__ rois,
    float* __restrict__ out)
{
    const int bid = blockIdx.x;
    const int r   = bid / PP;
    const int rem = bid % PP;
    const int i   = rem / P;
    const int j   = rem % P;
    const int q   = threadIdx.x;

    const float* roi = rois + (size_t)r * 5;
    const int b = (int)roi[0];
    int x0 = (int)rintf(roi[1] * 0.03125f);
    int y0 = (int)rintf(roi[2] * 0.03125f);
    int x1 = (int)rintf(roi[3] * 0.03125f);
    int y1 = (int)rintf(roi[4] * 0.03125f);
    x0 = min(max(x0, 0), W - 1);
    y0 = min(max(y0, 0), H - 1);
    x1 = min(max(x1, 0), W - 1);
    y1 = min(max(y1, 0), H - 1);

    float* o = out + (((size_t)r * C + q * 4) * P + i) * P + j;
    if (!((x0 < x1) && (y0 < y1))) {
        o[0] = 0.0f; o[PP] = 0.0f; o[2 * PP] = 0.0f; o[3 * PP] = 0.0f;
        return;
    }
    const int Lh = x1 - x0, Lw = y1 - y0;
    const int hs = x0 + (i * Lh) / P;
    const int he = x0 + ((i + 1) * Lh + (P - 1)) / P;
    const int ws = y0 + (j * Lw) / P;
    const int we = y0 + ((j + 1) * Lw + (P - 1)) / P;
    const int bh = he - hs, bw = we - ws;
    const ushort_t* base = ft + (((size_t)b * H + hs) * W + ws) * C + q * 4;
    float m0 = -INFINITY, m1 = -INFINITY, m2 = -INFINITY, m3 = -INFINITY;
    for (int h = 0; h < bh; h += 2) {
        const int h2 = min(h + 1, bh - 1);
        const ushort_t* r0 = base + (size_t)h  * (W * C);
        const ushort_t* r1 = base + (size_t)h2 * (W * C);
        for (int w = 0; w < bw; w += 2) {
            const int w2 = min(w + 1, bw - 1);
            const uint2 a  = *(const uint2*)(r0 + (size_t)w  * C);
            const uint2 bb = *(const uint2*)(r0 + (size_t)w2 * C);
            const uint2 cc = *(const uint2*)(r1 + (size_t)w  * C);
            const uint2 dd = *(const uint2*)(r1 + (size_t)w2 * C);
            m0 = fmaxf(fmaxf(fmaxf(m0, bflo(a.x)), fmaxf(bflo(bb.x), bflo(cc.x))), bflo(dd.x));
            m1 = fmaxf(fmaxf(fmaxf(m1, bfhi(a.x)), fmaxf(bfhi(bb.x), bfhi(cc.x))), bfhi(dd.x));
            m2 = fmaxf(fmaxf(fmaxf(m2, bflo(a.y)), fmaxf(bflo(bb.y), bflo(cc.y))), bflo(dd.y));
            m3 = fmaxf(fmaxf(fmaxf(m3, bfhi(a.y)), fmaxf(bfhi(bb.y), bfhi(cc.y))), bfhi(dd.y));
        }
    }
    o[0] = m0; o[PP] = m1; o[2 * PP] = m2; o[3 * PP] = m3;
}

// ---------------------------------------------------------------------------
// Fallback tier 2: no workspace (reads f32 features directly)
// ---------------------------------------------------------------------------
__global__ __launch_bounds__(256) void roi_pool_naive_kernel(
    const float* __restrict__ features, const float* __restrict__ rois,
    float* __restrict__ out)
{
    const int rb = blockIdx.x;
    const int r = rb / P;
    const int i = rb % P;
    const int c = threadIdx.x;

    const float* roi = rois + (size_t)r * 5;
    const int b = (int)roi[0];
    int x0 = (int)rintf(roi[1] * 0.03125f);
    int y0 = (int)rintf(roi[2] * 0.03125f);
    int x1 = (int)rintf(roi[3] * 0.03125f);
    int y1 = (int)rintf(roi[4] * 0.03125f);
    x0 = min(max(x0, 0), W - 1);
    y0 = min(max(y0, 0), H - 1);
    x1 = min(max(x1, 0), W - 1);
    y1 = min(max(y1, 0), H - 1);

    const bool valid = (x0 < x1) && (y0 < y1);
    float* o = out + (((size_t)r * C + c) * P + i) * P;
    if (!valid) {
        #pragma unroll
        for (int j = 0; j < P; ++j) o[j] = 0.0f;
        return;
    }
    const int Lh = x1 - x0, Lw = y1 - y0;
    const int hs = x0 + (i * Lh) / P;
    const int he = x0 + ((i + 1) * Lh + (P - 1)) / P;
    int ws_[P], we_[P];
    #pragma unroll
    for (int j = 0; j < P; ++j) {
        ws_[j] = y0 + (j * Lw) / P;
        we_[j] = y0 + ((j + 1) * Lw + (P - 1)) / P;
    }
    float acc[P];
    #pragma unroll
    for (int j = 0; j < P; ++j) acc[j] = -INFINITY;
    const float* f = features + (((size_t)b * C + c) * H) * W;
    for (int h = hs; h < he; ++h) {
        const float* row = f + h * W;
        #pragma unroll
        for (int j = 0; j < P; ++j) {
            float m = acc[j];
            for (int w = ws_[j]; w < we_[j]; ++w) m = fmaxf(m, row[w]);
            acc[j] = m;
        }
    }
    #pragma unroll
    for (int j = 0; j < P; ++j) o[j] = acc[j];
}

extern "C" void kernel_launch(void* const* d_in, const int* in_sizes, int n_in,
                              void* d_out, int out_size, void* d_ws, size_t ws_size,
                              hipStream_t stream)
{
    const float* features = (const float*)d_in[0];
    const float* rois     = (const float*)d_in[1];
    float* out = (float*)d_out;

    const int R = in_sizes[1] / 5;                  // 256
    const int N = in_sizes[0] / (C * S);            // 4

    const size_t ft_bytes   = (size_t)N * C * S * sizeof(ushort_t);   // 8 MB
    const size_t ws2_bytes  = (size_t)R * PP * C * sizeof(ushort_t);  // 6.4 MB
    const size_t perm_bytes = (size_t)R * sizeof(int);
    const size_t full_need  = ft_bytes + ws2_bytes + perm_bytes;

    if (ws_size >= full_need && R <= R_MAX) {
        ushort_t* ft  = (ushort_t*)d_ws;
        ushort_t* ws2 = (ushort_t*)((char*)d_ws + ft_bytes);
        int*     perm = (int*)((char*)d_ws + ft_bytes + ws2_bytes);

        dim3 tgrid(S / TT, C / TT, N);              // 64 x 4 x 4 = 1024 blocks
        transpose_bucket_kernel<<<tgrid, 256, 0, stream>>>(features, ft, rois, perm, R);
        roi_pool_cell_kernel<<<R * NCP, 128, 0, stream>>>(ft, rois, perm, ws2);
        reorder_kernel<<<R, 256, 0, stream>>>(ws2, perm, out);
    } else if (ws_size >= ft_bytes) {
        ushort_t* ft = (ushort_t*)d_ws;
        dim3 tgrid(S / TT, C / TT, N);
        transpose_bucket_kernel<<<tgrid, 256, 0, stream>>>(features, ft, rois, (int*)nullptr, 0);
        roi_pool_cell_direct_kernel<<<R * PP, 64, 0, stream>>>(ft, rois, out);
    } else {
        roi_pool_naive_kernel<<<R * P, C, 0, stream>>>(features, rois, out);
    }
}